// Round 6
// baseline (437.416 us; speedup 1.0000x reference)
//
#include <hip/hip_runtime.h>
#include <math.h>

#define BB 8
#define NN 2048
#define CC 128
#define KNB 16
#define BN (BB*NN)
#define PT 16          // points per GEMM tile
#define WSROW 132      // padded LDS row for W (16B-aligned, spreads banks)
#define CHALF 64       // c-dimension half staged per pass

#define EMPTYK 0xFFFFFFFFFFFFFFFFULL

__device__ __forceinline__ float silu_f(float x) { return x / (1.0f + expf(-x)); }

__device__ __forceinline__ unsigned long long umin64(unsigned long long a, unsigned long long b) {
  return (b < a) ? b : a;
}

// ---------------------------------------------------------------------------
// Kernel 1: kNN — one WAVE per query, 4 waves per 256-thread block, NO LDS,
// NO barriers. Packed key = (f64(d2) bits & ~2047) | m : u64-monotone on d2
// (d2>=0), unique, lower-index tie-break built in. Each lane holds its 32
// segment keys in VGPRs + a sorted top-4; extraction = 6-level u64 butterfly
// + masked shift in the owner lane; rare refill via register rescan.
// ---------------------------------------------------------------------------
__global__ __launch_bounds__(256) void knn_kernel(const float* __restrict__ x,
                                                  int* __restrict__ idx) {
  const int lane = threadIdx.x & 63;
  const int wave = threadIdx.x >> 6;
  const int bn = blockIdx.x * 4 + wave;
  const int b = bn >> 11;
  const int n = bn & (NN - 1);

  const float* xb = x + (size_t)b * NN * 3;
  const double xn0 = (double)xb[n*3+0], xn1 = (double)xb[n*3+1], xn2 = (double)xb[n*3+2];
  const double sqn = xn0*xn0 + xn1*xn1 + xn2*xn2;

  unsigned long long k[32];
  unsigned long long t0 = EMPTYK, t1 = EMPTYK, t2 = EMPTYK, t3 = EMPTYK;

  #pragma unroll
  for (int i = 0; i < 32; ++i) {
    const int m = i*64 + lane;
    const double a0 = (double)xb[m*3+0], a1 = (double)xb[m*3+1], a2 = (double)xb[m*3+2];
    const double sqm = a0*a0 + a1*a1 + a2*a2;
    const double dot = xn0*a0 + xn1*a1 + xn2*a2;
    const double d = sqn + sqm - 2.0*dot;
    unsigned long long kk =
        ((unsigned long long)__double_as_longlong(d) & ~2047ULL) | (unsigned long long)m;
    if (m == n) kk = 0x8000000000000000ULL | (unsigned long long)m;  // self: > all finite keys
    k[i] = kk;
    const bool l3 = kk < t3, l2 = kk < t2, l1 = kk < t1, l0 = kk < t0;
    t3 = l3 ? (l2 ? t2 : kk) : t3;
    t2 = l2 ? (l1 ? t1 : kk) : t2;
    t1 = l1 ? (l0 ? t0 : kk) : t1;
    t0 = l0 ? kk : t0;
  }

  int* op = idx + (size_t)bn * KNB;
  for (int t = 0; t < KNB; ++t) {
    unsigned long long g = t0;
    #pragma unroll
    for (int off = 32; off > 0; off >>= 1)
      g = umin64(g, (unsigned long long)__shfl_xor((unsigned long long)g, off, 64));

    if (lane == 0) op[t] = (int)(g & 2047ULL);

    const bool own = (t0 == g);
    t0 = own ? t1 : t0;
    t1 = own ? t2 : t1;
    t2 = own ? t3 : t2;
    t3 = own ? EMPTYK : t3;

    const bool need = (t0 == EMPTYK);
    if (__any(need)) {
      unsigned long long nm = EMPTYK;
      #pragma unroll
      for (int i = 0; i < 32; ++i) {
        const unsigned long long c = (k[i] > g) ? k[i] : EMPTYK;
        nm = umin64(nm, c);
      }
      t0 = need ? nm : t0;
    }
  }
}

// ---------------------------------------------------------------------------
// Kernel 2: Q/K/U GEMM, c-split staging. Ws holds 64 c-rows (33.8 KB) staged
// twice per tile from L2-hot W; Vs full tile (32 KB). LDS 65.8 KB -> 2
// blocks/CU = 2 waves/SIMD for latency hiding. Thread = (og,p): 24 accs.
// ---------------------------------------------------------------------------
__global__ __launch_bounds__(256, 2) void vn_linear_gemm(
    const float* __restrict__ v,
    const float* __restrict__ Wq, const float* __restrict__ Wk, const float* __restrict__ Wu,
    float* __restrict__ Q, float* __restrict__ Kt, float* __restrict__ U,
    float* __restrict__ qn, float* __restrict__ kn)
{
  const int mat = blockIdx.y;
  const float* __restrict__ W = (mat == 0) ? Wq : ((mat == 1) ? Wk : Wu);
  float* __restrict__ Out = (mat == 0) ? Q : ((mat == 1) ? Kt : U);

  __shared__ float Ws[CHALF][WSROW];  // 33.8 KB: [c-half][o]
  __shared__ float Vs[CC][PT*4];      // 32 KB:   [c][p*4+d]

  const int tid = threadIdx.x;
  const int og = tid & 15;
  const int p  = tid >> 4;
  const int obase = og * 8;

  float pre[24];
  const int t0 = blockIdx.x;
  {
    const float4* src = (const float4*)(v + (size_t)t0 * PT * (CC*3));
    #pragma unroll
    for (int it = 0; it < 6; ++it) {
      float4 f = src[tid + it*256];
      pre[it*4+0]=f.x; pre[it*4+1]=f.y; pre[it*4+2]=f.z; pre[it*4+3]=f.w;
    }
  }

  const float4* Wg = (const float4*)W;   // [o][c/4]

  for (int tt = 0; tt < 4; ++tt) {
    const int tile = t0 + tt*256;
    __syncthreads();                    // S1: previous compute done
    // scatter pre -> Vs
    #pragma unroll
    for (int it = 0; it < 6; ++it) {
      #pragma unroll
      for (int j = 0; j < 4; ++j) {
        const int g = (tid + it*256)*4 + j;
        const int pp = g / 384;
        const int r  = g - pp*384;
        const int c  = r / 3;
        const int d  = r - c*3;
        Vs[c][pp*4 + d] = pre[it*4+j];
      }
    }
    // stage W half 0
    #pragma unroll
    for (int i0 = 0; i0 < 2048; i0 += 256) {
      const int i = i0 + tid;
      const int o = i >> 4, q = i & 15;
      float4 f = Wg[o*32 + q];
      Ws[4*q+0][o]=f.x; Ws[4*q+1][o]=f.y; Ws[4*q+2][o]=f.z; Ws[4*q+3][o]=f.w;
    }
    __syncthreads();                    // S2

    if (tt < 3) {
      const float4* src = (const float4*)(v + (size_t)(tile + 256) * PT * (CC*3));
      #pragma unroll
      for (int it = 0; it < 6; ++it) {
        float4 f = src[tid + it*256];
        pre[it*4+0]=f.x; pre[it*4+1]=f.y; pre[it*4+2]=f.z; pre[it*4+3]=f.w;
      }
    }

    float acc[24];
    #pragma unroll
    for (int i = 0; i < 24; ++i) acc[i] = 0.f;

    #pragma unroll 4
    for (int c = 0; c < CHALF; ++c) {
      const float4 w0 = *(const float4*)&Ws[c][obase];
      const float4 w1 = *(const float4*)&Ws[c][obase+4];
      const float4 vv = *(const float4*)&Vs[c][p*4];
      const float wv[8] = {w0.x, w0.y, w0.z, w0.w, w1.x, w1.y, w1.z, w1.w};
      #pragma unroll
      for (int o = 0; o < 8; ++o) {
        acc[o*3+0] = fmaf(wv[o], vv.x, acc[o*3+0]);
        acc[o*3+1] = fmaf(wv[o], vv.y, acc[o*3+1]);
        acc[o*3+2] = fmaf(wv[o], vv.z, acc[o*3+2]);
      }
    }
    __syncthreads();                    // S3: half-0 readers done
    // stage W half 1
    #pragma unroll
    for (int i0 = 0; i0 < 2048; i0 += 256) {
      const int i = i0 + tid;
      const int o = i >> 4, q = i & 15;
      float4 f = Wg[o*32 + 16 + q];
      Ws[4*q+0][o]=f.x; Ws[4*q+1][o]=f.y; Ws[4*q+2][o]=f.z; Ws[4*q+3][o]=f.w;
    }
    __syncthreads();                    // S4

    #pragma unroll 4
    for (int c = 0; c < CHALF; ++c) {
      const float4 w0 = *(const float4*)&Ws[c][obase];
      const float4 w1 = *(const float4*)&Ws[c][obase+4];
      const float4 vv = *(const float4*)&Vs[CHALF + c][p*4];
      const float wv[8] = {w0.x, w0.y, w0.z, w0.w, w1.x, w1.y, w1.z, w1.w};
      #pragma unroll
      for (int o = 0; o < 8; ++o) {
        acc[o*3+0] = fmaf(wv[o], vv.x, acc[o*3+0]);
        acc[o*3+1] = fmaf(wv[o], vv.y, acc[o*3+1]);
        acc[o*3+2] = fmaf(wv[o], vv.z, acc[o*3+2]);
      }
    }

    const int point = tile * PT + p;
    if (mat < 2) {
      float nsum = 0.f;
      #pragma unroll
      for (int o = 0; o < 8; ++o)
        nsum += sqrtf(acc[o*3+0]*acc[o*3+0] + acc[o*3+1]*acc[o*3+1] + acc[o*3+2]*acc[o*3+2]);
      #pragma unroll
      for (int off = 8; off > 0; off >>= 1) nsum += __shfl_down(nsum, off, 16);
      if (og == 0) {
        if (mat == 0) qn[point] = nsum * (1.0f/128.0f);
        else          kn[point] = nsum * (1.0f/128.0f);
      }
    }

    float* opt = Out + (size_t)point * (CC*3) + obase*3;
    #pragma unroll
    for (int i = 0; i < 6; ++i) {
      float4 f = {acc[i*4+0], acc[i*4+1], acc[i*4+2], acc[i*4+3]};
      ((float4*)opt)[i] = f;
    }
  }
}

// ---------------------------------------------------------------------------
// Kernel 3: attention + message + VN layer norm + clamp. One block per point.
// U prefetched into registers right after nbr is known (gather latency hidden
// under phases 1-3); softmax inlined per-thread in phase 4 (one fewer barrier,
// no attnw LDS round-trip). XCD swizzle: batch = blockIdx%8.
// ---------------------------------------------------------------------------
__global__ __launch_bounds__(256, 4) void attn_kernel(
    const float* __restrict__ x, const int* __restrict__ idx,
    const float* __restrict__ Q, const float* __restrict__ Kt, const float* __restrict__ U,
    const float* __restrict__ qn, const float* __restrict__ kn,
    const float* __restrict__ W1, const float* __restrict__ b1,
    const float* __restrict__ W2, const float* __restrict__ b2,
    const float* __restrict__ W3, const float* __restrict__ b3,
    const float* __restrict__ gam, const float* __restrict__ bet,
    float* __restrict__ out)
{
  const int bid = blockIdx.x;
  const int bn = ((bid & 7) << 11) | (bid >> 3);   // batch = bid%8 = XCD id
  const int b = bn >> 11;
  const int tid = threadIdx.x;

  __shared__ __align__(16) float qs[CC*3];
  __shared__ int   nbr[KNB];
  __shared__ float sfeat[KNB][4];
  __shared__ float h1s[KNB][33];
  __shared__ float logits[KNB];
  __shared__ float red[4];
  __shared__ float red2[4];

  const float* Qp = Q + (size_t)bn * (CC*3);
  if (tid < 96) ((float4*)qs)[tid] = ((const float4*)Qp)[tid];
  if (tid < KNB) nbr[tid] = idx[(size_t)bn * KNB + tid];
  __syncthreads();

  // U prefetch into registers (tid<128): consumed after softmax; the 48
  // loads' latency is hidden under phases 1-3.
  float up0[KNB], up1[KNB], up2[KNB];
  if (tid < CC) {
    #pragma unroll
    for (int k2 = 0; k2 < KNB; ++k2) {
      const float* Up = U + ((size_t)(b * NN + nbr[k2])) * (CC*3) + tid*3;
      up0[k2] = Up[0]; up1[k2] = Up[1]; up2[k2] = Up[2];
    }
  }

  // Phase 1: Q.K dots (16 lanes per neighbor) + edge features
  {
    const int lane = tid & 63, wave = tid >> 6;
    const int kk = wave * 4 + (lane >> 4);
    const int sub = lane & 15;
    const int j = nbr[kk];
    const float* Kp = Kt + ((size_t)(b * NN + j)) * (CC*3);
    float acc = 0.f;
    #pragma unroll
    for (int q4 = 0; q4 < 6; ++q4) {
      const int off = sub * 24 + q4 * 4;
      float4 kv = *(const float4*)(Kp + off);
      acc += qs[off+0]*kv.x + qs[off+1]*kv.y + qs[off+2]*kv.z + qs[off+3]*kv.w;
    }
    #pragma unroll
    for (int off = 8; off > 0; off >>= 1) acc += __shfl_down(acc, off, 16);
    if (sub == 0) {
      const float xn0 = x[(size_t)bn*3+0], xn1 = x[(size_t)bn*3+1], xn2 = x[(size_t)bn*3+2];
      const size_t xj = (size_t)(b * NN + j) * 3;
      const float dx = xn0 - x[xj+0], dy = xn1 - x[xj+1], dz = xn2 - x[xj+2];
      sfeat[kk][0] = qn[bn];
      sfeat[kk][1] = kn[b * NN + j];
      sfeat[kk][2] = acc * (1.0f/128.0f);
      sfeat[kk][3] = sqrtf(dx*dx + dy*dy + dz*dz);
    }
  }
  __syncthreads();

  // Phase 2: edge MLP (16 neighbors x 16 threads)
  {
    const int k2 = tid >> 4;
    const int h = tid & 15;
    const float s0 = sfeat[k2][0], s1 = sfeat[k2][1], s2 = sfeat[k2][2], s3 = sfeat[k2][3];
    float u0 = b1[h]    + W1[h*4+0]*s0 + W1[h*4+1]*s1 + W1[h*4+2]*s2 + W1[h*4+3]*s3;
    float u1 = b1[h+16] + W1[(h+16)*4+0]*s0 + W1[(h+16)*4+1]*s1 + W1[(h+16)*4+2]*s2 + W1[(h+16)*4+3]*s3;
    h1s[k2][h]    = silu_f(u0);
    h1s[k2][h+16] = silu_f(u1);
  }
  __syncthreads();
  {
    const int k2 = tid >> 4;
    const int h = tid & 15;
    float a0 = b2[h], a1 = b2[h+16];
    #pragma unroll
    for (int c = 0; c < 32; ++c) {
      const float hv = h1s[k2][c];
      a0 = fmaf(W2[h*32+c], hv, a0);
      a1 = fmaf(W2[(h+16)*32+c], hv, a1);
    }
    a0 = silu_f(a0); a1 = silu_f(a1);
    float part = W3[h]*a0 + W3[h+16]*a1;
    #pragma unroll
    for (int off = 8; off > 0; off >>= 1) part += __shfl_down(part, off, 16);
    if (h == 0) {
      const float lg = part + b3[0];
      logits[k2] = fminf(fmaxf(lg, -10.0f), 10.0f);
    }
  }
  __syncthreads();

  // Phase 4: inline softmax + message (from prefetched regs) + residual +
  // VN layer norm + clamp (thread = channel o)
  float o0 = 0.f, o1 = 0.f, o2 = 0.f, nrm = 0.f;
  const bool act = tid < CC;
  if (act) {
    float lg[KNB];
    float mx = -1e30f;
    #pragma unroll
    for (int k2 = 0; k2 < KNB; ++k2) { lg[k2] = logits[k2]; mx = fmaxf(mx, lg[k2]); }
    float ssum = 0.f;
    float m0 = 0.f, m1 = 0.f, m2 = 0.f;
    #pragma unroll
    for (int k2 = 0; k2 < KNB; ++k2) {
      const float e = expf(lg[k2] - mx);
      ssum += e;
      m0 = fmaf(e, up0[k2], m0);
      m1 = fmaf(e, up1[k2], m1);
      m2 = fmaf(e, up2[k2], m2);
    }
    const float inv = 0.5f / ssum;       // fold RES_SCALE into normalization
    const int o = tid;
    o0 = qs[o*3+0] + inv*m0;
    o1 = qs[o*3+1] + inv*m1;
    o2 = qs[o*3+2] + inv*m2;
    nrm = fmaxf(sqrtf(o0*o0 + o1*o1 + o2*o2), 1e-6f);
  }
  {
    float s = nrm;
    #pragma unroll
    for (int off = 32; off > 0; off >>= 1) s += __shfl_down(s, off, 64);
    if ((tid & 63) == 0) red[tid >> 6] = s;
  }
  __syncthreads();
  const float mean = (red[0] + red[1] + red[2] + red[3]) * (1.0f/128.0f);
  const float dv = act ? (nrm - mean) : 0.f;
  {
    float s = dv * dv;
    #pragma unroll
    for (int off = 32; off > 0; off >>= 1) s += __shfl_down(s, off, 64);
    if ((tid & 63) == 0) red2[tid >> 6] = s;
  }
  __syncthreads();
  const float var = (red2[0] + red2[1] + red2[2] + red2[3]) * (1.0f/127.0f);
  const float stdv = fmaxf(sqrtf(var), 1e-6f);

  if (act) {
    const int o = tid;
    const float ns = (nrm - mean) / stdv * gam[o] + bet[o];
    const float sc1 = fmaxf(ns, 1e-6f) / nrm;
    float f0 = o0*sc1, f1 = o1*sc1, f2 = o2*sc1;
    const float n2 = fmaxf(sqrtf(f0*f0 + f1*f1 + f2*f2), 1e-6f);
    const float sc2 = fminf(50.0f / n2, 1.0f);
    float* op = out + (size_t)bn * (CC*3) + o*3;
    op[0] = f0*sc2; op[1] = f1*sc2; op[2] = f2*sc2;
  }
}

// ---------------------------------------------------------------------------
extern "C" void kernel_launch(void* const* d_in, const int* in_sizes, int n_in,
                              void* d_out, int out_size, void* d_ws, size_t ws_size,
                              hipStream_t stream) {
  (void)in_sizes; (void)n_in; (void)out_size; (void)ws_size;
  const float* x   = (const float*)d_in[0];
  const float* v   = (const float*)d_in[1];
  const float* Wq  = (const float*)d_in[2];
  const float* Wk  = (const float*)d_in[3];
  const float* Wu  = (const float*)d_in[4];
  const float* W1  = (const float*)d_in[5];
  const float* b1  = (const float*)d_in[6];
  const float* W2  = (const float*)d_in[7];
  const float* b2  = (const float*)d_in[8];
  const float* W3  = (const float*)d_in[9];
  const float* b3  = (const float*)d_in[10];
  const float* gam = (const float*)d_in[11];
  const float* bet = (const float*)d_in[12];
  float* out = (float*)d_out;

  char* ws = (char*)d_ws;
  int*   idx = (int*)ws;                                  // BN*16 ints (1 MB)
  float* Q   = (float*)(ws + (size_t)BN * KNB * 4);       // BN*384 floats
  float* Kt  = Q  + (size_t)BN * CC * 3;
  float* U   = Kt + (size_t)BN * CC * 3;
  float* qn  = U  + (size_t)BN * CC * 3;
  float* kn  = qn + BN;

  knn_kernel<<<BN/4, 256, 0, stream>>>(x, idx);
  vn_linear_gemm<<<dim3(256, 3), 256, 0, stream>>>(v, Wq, Wk, Wu, Q, Kt, U, qn, kn);
  attn_kernel<<<BN, 256, 0, stream>>>(x, idx, Q, Kt, U, qn, kn,
                                      W1, b1, W2, b2, W3, b3, gam, bet, out);
}

// Round 8
// 368.990 us; speedup vs baseline: 1.1854x; 1.1854x over previous
//
#include <hip/hip_runtime.h>
#include <math.h>

#define BB 8
#define NN 2048
#define CC 128
#define KNB 16
#define BN (BB*NN)
#define WPAD 136       // LDS row pad for W (16B-aligned rows, 2-way banks only)

#define EMPTYK 0xFFFFFFFFFFFFFFFFULL

typedef __attribute__((ext_vector_type(8))) short short8;
typedef __attribute__((ext_vector_type(4))) float floatx4;

__device__ __forceinline__ float silu_f(float x) { return x / (1.0f + expf(-x)); }

__device__ __forceinline__ unsigned long long umin64(unsigned long long a, unsigned long long b) {
  return (b < a) ? b : a;
}

__device__ __forceinline__ unsigned short f2bf(float f) {   // RNE
  unsigned u = __float_as_uint(f);
  unsigned r = u + 0x7FFFu + ((u >> 16) & 1u);
  return (unsigned short)(r >> 16);
}
__device__ __forceinline__ float bf2f(unsigned short s) {
  return __uint_as_float(((unsigned)s) << 16);
}

// ---------------------------------------------------------------------------
// Kernel 1: kNN — one WAVE per query, 4 waves/block, no LDS, no barriers.
// Packed key = (f64(d2) bits & ~2047) | m : u64-monotone on d2, unique,
// lower-index tie-break. Top-4 per lane in regs; rare register-rescan refill.
// ---------------------------------------------------------------------------
__global__ __launch_bounds__(256) void knn_kernel(const float* __restrict__ x,
                                                  int* __restrict__ idx) {
  const int lane = threadIdx.x & 63;
  const int wave = threadIdx.x >> 6;
  const int bn = blockIdx.x * 4 + wave;
  const int b = bn >> 11;
  const int n = bn & (NN - 1);

  const float* xb = x + (size_t)b * NN * 3;
  const double xn0 = (double)xb[n*3+0], xn1 = (double)xb[n*3+1], xn2 = (double)xb[n*3+2];
  const double sqn = xn0*xn0 + xn1*xn1 + xn2*xn2;

  unsigned long long k[32];
  unsigned long long t0 = EMPTYK, t1 = EMPTYK, t2 = EMPTYK, t3 = EMPTYK;

  #pragma unroll
  for (int i = 0; i < 32; ++i) {
    const int m = i*64 + lane;
    const double a0 = (double)xb[m*3+0], a1 = (double)xb[m*3+1], a2 = (double)xb[m*3+2];
    const double sqm = a0*a0 + a1*a1 + a2*a2;
    const double dot = xn0*a0 + xn1*a1 + xn2*a2;
    const double d = sqn + sqm - 2.0*dot;
    unsigned long long kk =
        ((unsigned long long)__double_as_longlong(d) & ~2047ULL) | (unsigned long long)m;
    if (m == n) kk = 0x8000000000000000ULL | (unsigned long long)m;
    k[i] = kk;
    const bool l3 = kk < t3, l2 = kk < t2, l1 = kk < t1, l0 = kk < t0;
    t3 = l3 ? (l2 ? t2 : kk) : t3;
    t2 = l2 ? (l1 ? t1 : kk) : t2;
    t1 = l1 ? (l0 ? t0 : kk) : t1;
    t0 = l0 ? kk : t0;
  }

  int* op = idx + (size_t)bn * KNB;
  for (int t = 0; t < KNB; ++t) {
    unsigned long long g = t0;
    #pragma unroll
    for (int off = 32; off > 0; off >>= 1)
      g = umin64(g, (unsigned long long)__shfl_xor((unsigned long long)g, off, 64));

    if (lane == 0) op[t] = (int)(g & 2047ULL);

    const bool own = (t0 == g);
    t0 = own ? t1 : t0;
    t1 = own ? t2 : t1;
    t2 = own ? t3 : t2;
    t3 = own ? EMPTYK : t3;

    const bool need = (t0 == EMPTYK);
    if (__any(need)) {
      unsigned long long nm = EMPTYK;
      #pragma unroll
      for (int i = 0; i < 32; ++i) {
        const unsigned long long c = (k[i] > g) ? k[i] : EMPTYK;
        nm = umin64(nm, c);
      }
      t0 = need ? nm : t0;
    }
  }
}

// ---------------------------------------------------------------------------
// Kernel 2: Q/K/U via bf16 split-precision MFMA (hi·Whi + lo·Whi + hi·Wlo;
// dropped lo·lo ~ 2^-18 rel). Rows = (point,dim) pairs (M=49152), cols = o.
// W hi/lo in LDS ([128][136] pad: o-stride 4 banks -> 2-way = free;
// 69.6 KB -> 2 blocks/CU). A fragments loaded per-lane from global BEFORE
// the single barrier (latency hidden; scatter absorbed by L1/L2).
// Wave = 16 rows x 128 cols: 8 tiles x f32x4 acc, 96 MFMA, 64 ds_read_b128.
// ---------------------------------------------------------------------------
__global__ __launch_bounds__(256, 2) void vn_gemm_mfma(
    const float* __restrict__ v,
    const float* __restrict__ Wq, const float* __restrict__ Wk, const float* __restrict__ Wu,
    float* __restrict__ Q, float* __restrict__ Kt, float* __restrict__ U)
{
  const int mat = blockIdx.y;
  const float* __restrict__ W = (mat == 0) ? Wq : ((mat == 1) ? Wk : Wu);
  float* __restrict__ Out = (mat == 0) ? Q : ((mat == 1) ? Kt : U);

  __shared__ short Wh[CC][WPAD];
  __shared__ short Wl[CC][WPAD];

  const int tid  = threadIdx.x;
  const int lane = tid & 63;
  const int wave = tid >> 6;
  const int quad = lane >> 4;
  const int l15  = lane & 15;

  // A loads first (independent of LDS): row m -> (p,d); 8 consecutive c per
  // quad per k-chunk, stride 3 floats in v.
  const int m = blockIdx.x*64 + wave*16 + l15;
  const int p = m / 3, d = m - 3*p;
  const float* vb = v + (size_t)p * (CC*3) + d;
  float areg[32];
  #pragma unroll
  for (int kc = 0; kc < 4; ++kc)
    #pragma unroll
    for (int j = 0; j < 8; ++j)
      areg[kc*8+j] = vb[(kc*32 + quad*8 + j)*3];

  // Stage W hi/lo to LDS (coalesced float4 reads, short4 LDS writes)
  {
    const float4* Wg = (const float4*)W;
    #pragma unroll
    for (int it = 0; it < 16; ++it) {
      const int i = tid + it*256;          // 4096 float4s
      const int o = i >> 5, c4 = (i & 31) * 4;
      float4 f = Wg[i];
      const float ff[4] = {f.x, f.y, f.z, f.w};
      short hs[4], ls[4];
      #pragma unroll
      for (int q = 0; q < 4; ++q) {
        unsigned short h = f2bf(ff[q]);
        float r = ff[q] - bf2f(h);
        hs[q] = (short)h;
        ls[q] = (short)f2bf(r);
      }
      *(short4*)&Wh[o][c4] = make_short4(hs[0], hs[1], hs[2], hs[3]);
      *(short4*)&Wl[o][c4] = make_short4(ls[0], ls[1], ls[2], ls[3]);
    }
  }

  // Convert A to hi/lo fragments (VALU, overlaps staging loads)
  short8 ah[4], al[4];
  #pragma unroll
  for (int kc = 0; kc < 4; ++kc)
    #pragma unroll
    for (int j = 0; j < 8; ++j) {
      const float f = areg[kc*8+j];
      unsigned short h = f2bf(f);
      float r = f - bf2f(h);
      ah[kc][j] = (short)h;
      al[kc][j] = (short)f2bf(r);
    }
  __syncthreads();

  floatx4 acc[8];
  #pragma unroll
  for (int ct = 0; ct < 8; ++ct) acc[ct] = (floatx4){0.f, 0.f, 0.f, 0.f};

  #pragma unroll
  for (int kc = 0; kc < 4; ++kc) {
    #pragma unroll
    for (int ct = 0; ct < 8; ++ct) {
      const int o = ct*16 + l15;
      const short8 bh = *(const short8*)&Wh[o][kc*32 + quad*8];
      const short8 bl = *(const short8*)&Wl[o][kc*32 + quad*8];
      acc[ct] = __builtin_amdgcn_mfma_f32_16x16x32_bf16(ah[kc], bh, acc[ct], 0, 0, 0);
      acc[ct] = __builtin_amdgcn_mfma_f32_16x16x32_bf16(al[kc], bh, acc[ct], 0, 0, 0);
      acc[ct] = __builtin_amdgcn_mfma_f32_16x16x32_bf16(ah[kc], bl, acc[ct], 0, 0, 0);
    }
  }

  // Epilogue: lane holds rows r0..r0+3 (quad*4+reg), col = ct*16+l15
  const int r0 = blockIdx.x*64 + wave*16 + quad*4;
  #pragma unroll
  for (int ct = 0; ct < 8; ++ct) {
    const int o = ct*16 + l15;
    #pragma unroll
    for (int reg = 0; reg < 4; ++reg) {
      const int r = r0 + reg;
      const int pp = r / 3, dd = r - 3*pp;
      Out[(size_t)pp * (CC*3) + o*3 + dd] = acc[ct][reg];
    }
  }
}

// ---------------------------------------------------------------------------
// Kernel 2b: qn/kn = mean over o of ||Q[p,o,:]|| (and K). One wave per point;
// lane handles 2 channels (6 consecutive floats).
// ---------------------------------------------------------------------------
__global__ __launch_bounds__(256) void norms_kernel(
    const float* __restrict__ Q, const float* __restrict__ Kt,
    float* __restrict__ qn, float* __restrict__ kn)
{
  const int lane = threadIdx.x & 63;
  const int pnt = blockIdx.x * 4 + (threadIdx.x >> 6);

  const float* Qp = Q + (size_t)pnt * (CC*3) + lane*6;
  float s = 0.f;
  {
    const float x0=Qp[0],x1=Qp[1],x2=Qp[2],x3=Qp[3],x4=Qp[4],x5=Qp[5];
    s = sqrtf(x0*x0+x1*x1+x2*x2) + sqrtf(x3*x3+x4*x4+x5*x5);
  }
  #pragma unroll
  for (int off = 32; off > 0; off >>= 1) s += __shfl_xor(s, off, 64);
  if (lane == 0) qn[pnt] = s * (1.0f/128.0f);

  const float* Kp = Kt + (size_t)pnt * (CC*3) + lane*6;
  float s2 = 0.f;
  {
    const float x0=Kp[0],x1=Kp[1],x2=Kp[2],x3=Kp[3],x4=Kp[4],x5=Kp[5];
    s2 = sqrtf(x0*x0+x1*x1+x2*x2) + sqrtf(x3*x3+x4*x4+x5*x5);
  }
  #pragma unroll
  for (int off = 32; off > 0; off >>= 1) s2 += __shfl_xor(s2, off, 64);
  if (lane == 0) kn[pnt] = s2 * (1.0f/128.0f);
}

// ---------------------------------------------------------------------------
// Kernel 3: attention + message + VN layer norm + clamp (round-5 proven
// structure: LDS softmax, direct U gather in phase 4, XCD swizzle).
// ---------------------------------------------------------------------------
__global__ __launch_bounds__(256) void attn_kernel(
    const float* __restrict__ x, const int* __restrict__ idx,
    const float* __restrict__ Q, const float* __restrict__ Kt, const float* __restrict__ U,
    const float* __restrict__ qn, const float* __restrict__ kn,
    const float* __restrict__ W1, const float* __restrict__ b1,
    const float* __restrict__ W2, const float* __restrict__ b2,
    const float* __restrict__ W3, const float* __restrict__ b3,
    const float* __restrict__ gam, const float* __restrict__ bet,
    float* __restrict__ out)
{
  const int bid = blockIdx.x;
  const int bn = ((bid & 7) << 11) | (bid >> 3);   // batch = bid%8 = XCD id
  const int b = bn >> 11;
  const int tid = threadIdx.x;

  __shared__ __align__(16) float qs[CC*3];
  __shared__ int   nbr[KNB];
  __shared__ float sfeat[KNB][4];
  __shared__ float h1s[KNB][33];
  __shared__ float logits[KNB];
  __shared__ float attnw[KNB];
  __shared__ float red[4];
  __shared__ float red2[4];

  const float* Qp = Q + (size_t)bn * (CC*3);
  if (tid < 96) ((float4*)qs)[tid] = ((const float4*)Qp)[tid];
  if (tid < KNB) nbr[tid] = idx[(size_t)bn * KNB + tid];
  __syncthreads();

  // Phase 1: Q.K dots (16 lanes per neighbor) + edge features
  {
    const int lane = tid & 63, wave = tid >> 6;
    const int kk = wave * 4 + (lane >> 4);
    const int sub = lane & 15;
    const int j = nbr[kk];
    const float* Kp = Kt + ((size_t)(b * NN + j)) * (CC*3);
    float acc = 0.f;
    #pragma unroll
    for (int q4 = 0; q4 < 6; ++q4) {
      const int off = sub * 24 + q4 * 4;
      float4 kv = *(const float4*)(Kp + off);
      acc += qs[off+0]*kv.x + qs[off+1]*kv.y + qs[off+2]*kv.z + qs[off+3]*kv.w;
    }
    #pragma unroll
    for (int off = 8; off > 0; off >>= 1) acc += __shfl_down(acc, off, 16);
    if (sub == 0) {
      const float xn0 = x[(size_t)bn*3+0], xn1 = x[(size_t)bn*3+1], xn2 = x[(size_t)bn*3+2];
      const size_t xj = (size_t)(b * NN + j) * 3;
      const float dx = xn0 - x[xj+0], dy = xn1 - x[xj+1], dz = xn2 - x[xj+2];
      sfeat[kk][0] = qn[bn];
      sfeat[kk][1] = kn[b * NN + j];
      sfeat[kk][2] = acc * (1.0f/128.0f);
      sfeat[kk][3] = sqrtf(dx*dx + dy*dy + dz*dz);
    }
  }
  __syncthreads();

  // Phase 2: edge MLP (16 neighbors x 16 threads)
  {
    const int k2 = tid >> 4;
    const int h = tid & 15;
    const float s0 = sfeat[k2][0], s1 = sfeat[k2][1], s2 = sfeat[k2][2], s3 = sfeat[k2][3];
    float u0 = b1[h]    + W1[h*4+0]*s0 + W1[h*4+1]*s1 + W1[h*4+2]*s2 + W1[h*4+3]*s3;
    float u1 = b1[h+16] + W1[(h+16)*4+0]*s0 + W1[(h+16)*4+1]*s1 + W1[(h+16)*4+2]*s2 + W1[(h+16)*4+3]*s3;
    h1s[k2][h]    = silu_f(u0);
    h1s[k2][h+16] = silu_f(u1);
  }
  __syncthreads();
  {
    const int k2 = tid >> 4;
    const int h = tid & 15;
    float a0 = b2[h], a1 = b2[h+16];
    #pragma unroll
    for (int c = 0; c < 32; ++c) {
      const float hv = h1s[k2][c];
      a0 = fmaf(W2[h*32+c], hv, a0);
      a1 = fmaf(W2[(h+16)*32+c], hv, a1);
    }
    a0 = silu_f(a0); a1 = silu_f(a1);
    float part = W3[h]*a0 + W3[h+16]*a1;
    #pragma unroll
    for (int off = 8; off > 0; off >>= 1) part += __shfl_down(part, off, 16);
    if (h == 0) {
      const float lg = part + b3[0];
      logits[k2] = fminf(fmaxf(lg, -10.0f), 10.0f);
    }
  }
  __syncthreads();

  // Phase 3: softmax over 16 neighbors
  if (tid < KNB) {
    const float l = logits[tid];
    float m = l;
    #pragma unroll
    for (int off = 8; off > 0; off >>= 1) m = fmaxf(m, __shfl_xor(m, off, 16));
    const float e = expf(l - m);
    float ssum = e;
    #pragma unroll
    for (int off = 8; off > 0; off >>= 1) ssum += __shfl_xor(ssum, off, 16);
    attnw[tid] = e / ssum;
  }
  __syncthreads();

  // Phase 4: message + residual + VN layer norm + clamp (thread = channel o)
  float o0 = 0.f, o1 = 0.f, o2 = 0.f, nrm = 0.f;
  const bool act = tid < CC;
  if (act) {
    const int o = tid;
    float m0 = 0.f, m1 = 0.f, m2 = 0.f;
    #pragma unroll
    for (int k2 = 0; k2 < KNB; ++k2) {
      const int j = nbr[k2];
      const float* Up = U + ((size_t)(b * NN + j)) * (CC*3) + o*3;
      const float a = attnw[k2];
      m0 = fmaf(a, Up[0], m0);
      m1 = fmaf(a, Up[1], m1);
      m2 = fmaf(a, Up[2], m2);
    }
    o0 = qs[o*3+0] + 0.5f*m0;
    o1 = qs[o*3+1] + 0.5f*m1;
    o2 = qs[o*3+2] + 0.5f*m2;
    nrm = fmaxf(sqrtf(o0*o0 + o1*o1 + o2*o2), 1e-6f);
  }
  {
    float s = nrm;
    #pragma unroll
    for (int off = 32; off > 0; off >>= 1) s += __shfl_down(s, off, 64);
    if ((tid & 63) == 0) red[tid >> 6] = s;
  }
  __syncthreads();
  const float mean = (red[0] + red[1] + red[2] + red[3]) * (1.0f/128.0f);
  const float dv = act ? (nrm - mean) : 0.f;
  {
    float s = dv * dv;
    #pragma unroll
    for (int off = 32; off > 0; off >>= 1) s += __shfl_down(s, off, 64);
    if ((tid & 63) == 0) red2[tid >> 6] = s;
  }
  __syncthreads();
  const float var = (red2[0] + red2[1] + red2[2] + red2[3]) * (1.0f/127.0f);
  const float stdv = fmaxf(sqrtf(var), 1e-6f);

  if (act) {
    const int o = tid;
    const float ns = (nrm - mean) / stdv * gam[o] + bet[o];
    const float sc1 = fmaxf(ns, 1e-6f) / nrm;
    float f0 = o0*sc1, f1 = o1*sc1, f2 = o2*sc1;
    const float n2 = fmaxf(sqrtf(f0*f0 + f1*f1 + f2*f2), 1e-6f);
    const float sc2 = fminf(50.0f / n2, 1.0f);
    float* op = out + (size_t)bn * (CC*3) + o*3;
    op[0] = f0*sc2; op[1] = f1*sc2; op[2] = f2*sc2;
  }
}

// ---------------------------------------------------------------------------
extern "C" void kernel_launch(void* const* d_in, const int* in_sizes, int n_in,
                              void* d_out, int out_size, void* d_ws, size_t ws_size,
                              hipStream_t stream) {
  (void)in_sizes; (void)n_in; (void)out_size; (void)ws_size;
  const float* x   = (const float*)d_in[0];
  const float* v   = (const float*)d_in[1];
  const float* Wq  = (const float*)d_in[2];
  const float* Wk  = (const float*)d_in[3];
  const float* Wu  = (const float*)d_in[4];
  const float* W1  = (const float*)d_in[5];
  const float* b1  = (const float*)d_in[6];
  const float* W2  = (const float*)d_in[7];
  const float* b2  = (const float*)d_in[8];
  const float* W3  = (const float*)d_in[9];
  const float* b3  = (const float*)d_in[10];
  const float* gam = (const float*)d_in[11];
  const float* bet = (const float*)d_in[12];
  float* out = (float*)d_out;

  char* ws = (char*)d_ws;
  int*   idx = (int*)ws;                                  // BN*16 ints (1 MB)
  float* Q   = (float*)(ws + (size_t)BN * KNB * 4);       // BN*384 floats
  float* Kt  = Q  + (size_t)BN * CC * 3;
  float* U   = Kt + (size_t)BN * CC * 3;
  float* qn  = U  + (size_t)BN * CC * 3;
  float* kn  = qn + BN;

  knn_kernel<<<BN/4, 256, 0, stream>>>(x, idx);
  vn_gemm_mfma<<<dim3((BN*3)/64, 3), 256, 0, stream>>>(v, Wq, Wk, Wu, Q, Kt, U);
  norms_kernel<<<BN/4, 256, 0, stream>>>(Q, Kt, qn, kn);
  attn_kernel<<<BN, 256, 0, stream>>>(x, idx, Q, Kt, U, qn, kn,
                                      W1, b1, W2, b2, W3, b3, gam, bet, out);
}

// Round 9
// 326.732 us; speedup vs baseline: 1.3388x; 1.1293x over previous
//
#include <hip/hip_runtime.h>
#include <math.h>

#define BB 8
#define NN 2048
#define CC 128
#define KNB 16
#define BN (BB*NN)
#define WPAD 136       // LDS row pad for W (16B-aligned rows, 2-way banks only)

#define EMPTYK 0xFFFFFFFFFFFFFFFFULL

typedef __attribute__((ext_vector_type(8))) short short8;
typedef __attribute__((ext_vector_type(4))) float floatx4;

__device__ __forceinline__ float silu_f(float x) { return x / (1.0f + expf(-x)); }

__device__ __forceinline__ unsigned long long umin64(unsigned long long a, unsigned long long b) {
  return (b < a) ? b : a;
}

__device__ __forceinline__ unsigned short f2bf(float f) {   // RNE
  unsigned u = __float_as_uint(f);
  unsigned r = u + 0x7FFFu + ((u >> 16) & 1u);
  return (unsigned short)(r >> 16);
}
__device__ __forceinline__ float bf2f(unsigned short s) {
  return __uint_as_float(((unsigned)s) << 16);
}

// ---------------------------------------------------------------------------
// Kernel 1: kNN — one WAVE per query, 4 waves/block, no LDS, no barriers.
// Packed key = (f64(d2) bits & ~2047) | m : u64-monotone on d2, unique,
// lower-index tie-break. Top-4 per lane in regs; rare register-rescan refill.
// ---------------------------------------------------------------------------
__global__ __launch_bounds__(256) void knn_kernel(const float* __restrict__ x,
                                                  int* __restrict__ idx) {
  const int lane = threadIdx.x & 63;
  const int wave = threadIdx.x >> 6;
  const int bn = blockIdx.x * 4 + wave;
  const int b = bn >> 11;
  const int n = bn & (NN - 1);

  const float* xb = x + (size_t)b * NN * 3;
  const double xn0 = (double)xb[n*3+0], xn1 = (double)xb[n*3+1], xn2 = (double)xb[n*3+2];
  const double sqn = xn0*xn0 + xn1*xn1 + xn2*xn2;

  unsigned long long k[32];
  unsigned long long t0 = EMPTYK, t1 = EMPTYK, t2 = EMPTYK, t3 = EMPTYK;

  #pragma unroll
  for (int i = 0; i < 32; ++i) {
    const int m = i*64 + lane;
    const double a0 = (double)xb[m*3+0], a1 = (double)xb[m*3+1], a2 = (double)xb[m*3+2];
    const double sqm = a0*a0 + a1*a1 + a2*a2;
    const double dot = xn0*a0 + xn1*a1 + xn2*a2;
    const double d = sqn + sqm - 2.0*dot;
    unsigned long long kk =
        ((unsigned long long)__double_as_longlong(d) & ~2047ULL) | (unsigned long long)m;
    if (m == n) kk = 0x8000000000000000ULL | (unsigned long long)m;
    k[i] = kk;
    const bool l3 = kk < t3, l2 = kk < t2, l1 = kk < t1, l0 = kk < t0;
    t3 = l3 ? (l2 ? t2 : kk) : t3;
    t2 = l2 ? (l1 ? t1 : kk) : t2;
    t1 = l1 ? (l0 ? t0 : kk) : t1;
    t0 = l0 ? kk : t0;
  }

  int* op = idx + (size_t)bn * KNB;
  for (int t = 0; t < KNB; ++t) {
    unsigned long long g = t0;
    #pragma unroll
    for (int off = 32; off > 0; off >>= 1)
      g = umin64(g, (unsigned long long)__shfl_xor((unsigned long long)g, off, 64));

    if (lane == 0) op[t] = (int)(g & 2047ULL);

    const bool own = (t0 == g);
    t0 = own ? t1 : t0;
    t1 = own ? t2 : t1;
    t2 = own ? t3 : t2;
    t3 = own ? EMPTYK : t3;

    const bool need = (t0 == EMPTYK);
    if (__any(need)) {
      unsigned long long nm = EMPTYK;
      #pragma unroll
      for (int i = 0; i < 32; ++i) {
        const unsigned long long c = (k[i] > g) ? k[i] : EMPTYK;
        nm = umin64(nm, c);
      }
      t0 = need ? nm : t0;
    }
  }
}

// ---------------------------------------------------------------------------
// Kernel 2: Q/K/U via bf16 split-precision MFMA (hi·Whi + lo·Whi + hi·Wlo).
// W hi/lo in LDS; A per-lane from global before the single barrier.
// ---------------------------------------------------------------------------
__global__ __launch_bounds__(256, 2) void vn_gemm_mfma(
    const float* __restrict__ v,
    const float* __restrict__ Wq, const float* __restrict__ Wk, const float* __restrict__ Wu,
    float* __restrict__ Q, float* __restrict__ Kt, float* __restrict__ U)
{
  const int mat = blockIdx.y;
  const float* __restrict__ W = (mat == 0) ? Wq : ((mat == 1) ? Wk : Wu);
  float* __restrict__ Out = (mat == 0) ? Q : ((mat == 1) ? Kt : U);

  __shared__ short Wh[CC][WPAD];
  __shared__ short Wl[CC][WPAD];

  const int tid  = threadIdx.x;
  const int lane = tid & 63;
  const int wave = tid >> 6;
  const int quad = lane >> 4;
  const int l15  = lane & 15;

  const int m = blockIdx.x*64 + wave*16 + l15;
  const int p = m / 3, d = m - 3*p;
  const float* vb = v + (size_t)p * (CC*3) + d;
  float areg[32];
  #pragma unroll
  for (int kc = 0; kc < 4; ++kc)
    #pragma unroll
    for (int j = 0; j < 8; ++j)
      areg[kc*8+j] = vb[(kc*32 + quad*8 + j)*3];

  {
    const float4* Wg = (const float4*)W;
    #pragma unroll
    for (int it = 0; it < 16; ++it) {
      const int i = tid + it*256;
      const int o = i >> 5, c4 = (i & 31) * 4;
      float4 f = Wg[i];
      const float ff[4] = {f.x, f.y, f.z, f.w};
      short hs[4], ls[4];
      #pragma unroll
      for (int q = 0; q < 4; ++q) {
        unsigned short h = f2bf(ff[q]);
        float r = ff[q] - bf2f(h);
        hs[q] = (short)h;
        ls[q] = (short)f2bf(r);
      }
      *(short4*)&Wh[o][c4] = make_short4(hs[0], hs[1], hs[2], hs[3]);
      *(short4*)&Wl[o][c4] = make_short4(ls[0], ls[1], ls[2], ls[3]);
    }
  }

  short8 ah[4], al[4];
  #pragma unroll
  for (int kc = 0; kc < 4; ++kc)
    #pragma unroll
    for (int j = 0; j < 8; ++j) {
      const float f = areg[kc*8+j];
      unsigned short h = f2bf(f);
      float r = f - bf2f(h);
      ah[kc][j] = (short)h;
      al[kc][j] = (short)f2bf(r);
    }
  __syncthreads();

  floatx4 acc[8];
  #pragma unroll
  for (int ct = 0; ct < 8; ++ct) acc[ct] = (floatx4){0.f, 0.f, 0.f, 0.f};

  #pragma unroll
  for (int kc = 0; kc < 4; ++kc) {
    #pragma unroll
    for (int ct = 0; ct < 8; ++ct) {
      const int o = ct*16 + l15;
      const short8 bh = *(const short8*)&Wh[o][kc*32 + quad*8];
      const short8 bl = *(const short8*)&Wl[o][kc*32 + quad*8];
      acc[ct] = __builtin_amdgcn_mfma_f32_16x16x32_bf16(ah[kc], bh, acc[ct], 0, 0, 0);
      acc[ct] = __builtin_amdgcn_mfma_f32_16x16x32_bf16(al[kc], bh, acc[ct], 0, 0, 0);
      acc[ct] = __builtin_amdgcn_mfma_f32_16x16x32_bf16(ah[kc], bl, acc[ct], 0, 0, 0);
    }
  }

  const int r0 = blockIdx.x*64 + wave*16 + quad*4;
  #pragma unroll
  for (int ct = 0; ct < 8; ++ct) {
    const int o = ct*16 + l15;
    #pragma unroll
    for (int reg = 0; reg < 4; ++reg) {
      const int r = r0 + reg;
      const int pp = r / 3, dd = r - 3*pp;
      Out[(size_t)pp * (CC*3) + o*3 + dd] = acc[ct][reg];
    }
  }
}

// ---------------------------------------------------------------------------
// Kernel 3: attention, WAVE-PER-POINT, ZERO barriers. Lane = 2 channels.
// Neighbor idx via wave-uniform loads (SGPR bases for gathers); QK dots +
// per-neighbor kn + qn fused in one 33-payload 64-lane butterfly (norms
// kernel eliminated); U prefetched into regs before the MLP (latency hidden
// under ~3K cycles of MLP VALU with no intervening barrier); edge MLP
// computed on all 64 lanes (weights at uniform addresses -> s_load);
// softmax in 16-lane groups; message/residual/VN-norm/clamp per lane.
// ---------------------------------------------------------------------------
__global__ __launch_bounds__(256) void attn_wave_kernel(
    const float* __restrict__ x, const int* __restrict__ idx,
    const float* __restrict__ Q, const float* __restrict__ Kt, const float* __restrict__ U,
    const float* __restrict__ W1, const float* __restrict__ b1,
    const float* __restrict__ W2, const float* __restrict__ b2,
    const float* __restrict__ W3, const float* __restrict__ b3,
    const float* __restrict__ gam, const float* __restrict__ bet,
    float* __restrict__ out)
{
  const int lane = threadIdx.x & 63;
  const int wv   = threadIdx.x >> 6;
  // XCD swizzle: batch = blockIdx%8 (all 4 waves of a block share a batch)
  const int bn = ((blockIdx.x & 7) << 11) | (((blockIdx.x >> 3) << 2) | wv);
  const int b = bn >> 11;

  // Q for this lane's 2 channels (6 floats) + neighbor indices (uniform)
  const float* Qp = Q + (size_t)bn * (CC*3) + lane*6;
  const float2 qa = *(const float2*)Qp;
  const float2 qb = *(const float2*)(Qp+2);
  const float2 qc = *(const float2*)(Qp+4);

  const int* ip = idx + (size_t)bn * KNB;
  int j[KNB];
  #pragma unroll
  for (int t = 0; t < KNB; ++t) j[t] = ip[t];

  // K gather + dot partials + kn partials; qn partial from Q
  float dpart[KNB], knp[KNB];
  #pragma unroll
  for (int t = 0; t < KNB; ++t) {
    const float* Kp = Kt + (size_t)(b*NN + j[t]) * (CC*3) + lane*6;
    const float2 a = *(const float2*)Kp;
    const float2 bb = *(const float2*)(Kp+2);
    const float2 c = *(const float2*)(Kp+4);
    dpart[t] = qa.x*a.x + qa.y*a.y + qb.x*bb.x + qb.y*bb.y + qc.x*c.x + qc.y*c.y;
    knp[t] = sqrtf(a.x*a.x + a.y*a.y + bb.x*bb.x) + sqrtf(bb.y*bb.y + c.x*c.x + c.y*c.y);
  }
  float qnp = sqrtf(qa.x*qa.x + qa.y*qa.y + qb.x*qb.x) + sqrtf(qb.y*qb.y + qc.x*qc.x + qc.y*qc.y);

  // one 33-payload butterfly over 64 lanes
  #pragma unroll
  for (int off = 1; off < 64; off <<= 1) {
    #pragma unroll
    for (int t = 0; t < KNB; ++t) {
      dpart[t] += __shfl_xor(dpart[t], off, 64);
      knp[t]   += __shfl_xor(knp[t], off, 64);
    }
    qnp += __shfl_xor(qnp, off, 64);
  }
  const float qn_i = qnp * (1.0f/128.0f);

  // per-lane neighbor select (kk = lane&15) via cndmask tree
  const int kk = lane & 15;
  int jsel = j[0];
  float dsel = dpart[0], knsel = knp[0];
  #pragma unroll
  for (int t = 1; t < KNB; ++t) {
    const bool c = (kk == t);
    jsel  = c ? j[t] : jsel;
    dsel  = c ? dpart[t] : dsel;
    knsel = c ? knp[t] : knsel;
  }

  // dist feature
  const float xi0 = x[(size_t)bn*3+0], xi1 = x[(size_t)bn*3+1], xi2 = x[(size_t)bn*3+2];
  const float* xj = x + (size_t)(b*NN + jsel)*3;
  const float dx = xi0 - xj[0], dy = xi1 - xj[1], dz = xi2 - xj[2];
  const float s3 = sqrtf(dx*dx + dy*dy + dz*dz);
  const float s0 = qn_i;
  const float s1 = knsel * (1.0f/128.0f);
  const float s2 = dsel * (1.0f/128.0f);

  // issue U gather NOW (consumed after softmax; latency hides under MLP)
  float u0[KNB], u1[KNB], u2[KNB], u3[KNB], u4[KNB], u5[KNB];
  #pragma unroll
  for (int t = 0; t < KNB; ++t) {
    const float* Up = U + (size_t)(b*NN + j[t]) * (CC*3) + lane*6;
    const float2 a = *(const float2*)Up;
    const float2 bb = *(const float2*)(Up+2);
    const float2 c = *(const float2*)(Up+4);
    u0[t]=a.x; u1[t]=a.y; u2[t]=bb.x; u3[t]=bb.y; u4[t]=c.x; u5[t]=c.y;
  }

  // edge MLP (all lanes; weights at uniform addresses -> scalar loads)
  float h1[32];
  #pragma unroll
  for (int h = 0; h < 32; ++h) {
    const float u = b1[h] + W1[h*4+0]*s0 + W1[h*4+1]*s1 + W1[h*4+2]*s2 + W1[h*4+3]*s3;
    h1[h] = silu_f(u);
  }
  float logit = b3[0];
  #pragma unroll
  for (int h = 0; h < 32; ++h) {
    float a = b2[h];
    #pragma unroll
    for (int c = 0; c < 32; ++c) a = fmaf(W2[h*32+c], h1[c], a);
    logit = fmaf(W3[h], silu_f(a), logit);
  }
  logit = fminf(fmaxf(logit, -10.0f), 10.0f);

  // softmax over the 16-lane group
  float mx = logit;
  #pragma unroll
  for (int off = 8; off > 0; off >>= 1) mx = fmaxf(mx, __shfl_xor(mx, off, 16));
  const float e = expf(logit - mx);
  float ssum = e;
  #pragma unroll
  for (int off = 8; off > 0; off >>= 1) ssum += __shfl_xor(ssum, off, 16);
  const float w = e / ssum;

  // broadcast the 16 weights to all lanes
  float wk[KNB];
  #pragma unroll
  for (int t = 0; t < KNB; ++t) wk[t] = __shfl(w, t, 64);

  // message + residual
  float m0=0.f,m1=0.f,m2=0.f,m3=0.f,m4=0.f,m5=0.f;
  #pragma unroll
  for (int t = 0; t < KNB; ++t) {
    const float ww = wk[t];
    m0 = fmaf(ww, u0[t], m0); m1 = fmaf(ww, u1[t], m1); m2 = fmaf(ww, u2[t], m2);
    m3 = fmaf(ww, u3[t], m3); m4 = fmaf(ww, u4[t], m4); m5 = fmaf(ww, u5[t], m5);
  }
  const float oa0 = qa.x + 0.5f*m0, oa1 = qa.y + 0.5f*m1, oa2 = qb.x + 0.5f*m2;
  const float ob0 = qb.y + 0.5f*m3, ob1 = qc.x + 0.5f*m4, ob2 = qc.y + 0.5f*m5;

  // VN layer norm (two channels per lane)
  const float na = fmaxf(sqrtf(oa0*oa0 + oa1*oa1 + oa2*oa2), 1e-6f);
  const float nb = fmaxf(sqrtf(ob0*ob0 + ob1*ob1 + ob2*ob2), 1e-6f);
  float s = na + nb;
  #pragma unroll
  for (int off = 1; off < 64; off <<= 1) s += __shfl_xor(s, off, 64);
  const float mean = s * (1.0f/128.0f);
  const float dva = na - mean, dvb = nb - mean;
  float s2v = dva*dva + dvb*dvb;
  #pragma unroll
  for (int off = 1; off < 64; off <<= 1) s2v += __shfl_xor(s2v, off, 64);
  const float stdv = fmaxf(sqrtf(s2v * (1.0f/127.0f)), 1e-6f);

  const float2 gm = *(const float2*)(gam + lane*2);
  const float2 bt = *(const float2*)(bet + lane*2);
  const float nsa = (na - mean) / stdv * gm.x + bt.x;
  const float nsb = (nb - mean) / stdv * gm.y + bt.y;
  const float sca = fmaxf(nsa, 1e-6f) / na;
  const float scb = fmaxf(nsb, 1e-6f) / nb;
  float fa0 = oa0*sca, fa1 = oa1*sca, fa2 = oa2*sca;
  float fb0 = ob0*scb, fb1 = ob1*scb, fb2 = ob2*scb;
  const float n2a = fmaxf(sqrtf(fa0*fa0 + fa1*fa1 + fa2*fa2), 1e-6f);
  const float n2b = fmaxf(sqrtf(fb0*fb0 + fb1*fb1 + fb2*fb2), 1e-6f);
  const float c2a = fminf(50.0f / n2a, 1.0f);
  const float c2b = fminf(50.0f / n2b, 1.0f);

  float* op = out + (size_t)bn * (CC*3) + lane*6;
  *(float2*)op     = make_float2(fa0*c2a, fa1*c2a);
  *(float2*)(op+2) = make_float2(fa2*c2a, fb0*c2b);
  *(float2*)(op+4) = make_float2(fb1*c2b, fb2*c2b);
}

// ---------------------------------------------------------------------------
extern "C" void kernel_launch(void* const* d_in, const int* in_sizes, int n_in,
                              void* d_out, int out_size, void* d_ws, size_t ws_size,
                              hipStream_t stream) {
  (void)in_sizes; (void)n_in; (void)out_size; (void)ws_size;
  const float* x   = (const float*)d_in[0];
  const float* v   = (const float*)d_in[1];
  const float* Wq  = (const float*)d_in[2];
  const float* Wk  = (const float*)d_in[3];
  const float* Wu  = (const float*)d_in[4];
  const float* W1  = (const float*)d_in[5];
  const float* b1  = (const float*)d_in[6];
  const float* W2  = (const float*)d_in[7];
  const float* b2  = (const float*)d_in[8];
  const float* W3  = (const float*)d_in[9];
  const float* b3  = (const float*)d_in[10];
  const float* gam = (const float*)d_in[11];
  const float* bet = (const float*)d_in[12];
  float* out = (float*)d_out;

  char* ws = (char*)d_ws;
  int*   idx = (int*)ws;                                  // BN*16 ints (1 MB)
  float* Q   = (float*)(ws + (size_t)BN * KNB * 4);       // BN*384 floats
  float* Kt  = Q  + (size_t)BN * CC * 3;
  float* U   = Kt + (size_t)BN * CC * 3;

  knn_kernel<<<BN/4, 256, 0, stream>>>(x, idx);
  vn_gemm_mfma<<<dim3((BN*3)/64, 3), 256, 0, stream>>>(v, Wq, Wk, Wu, Q, Kt, U);
  attn_wave_kernel<<<BN/4, 256, 0, stream>>>(x, idx, Q, Kt, U,
                                             W1, b1, W2, b2, W3, b3, gam, bet, out);
}